// Round 6
// baseline (437.005 us; speedup 1.0000x reference)
//
#include <hip/hip_runtime.h>
#include <hip/hip_bf16.h>
#include <math.h>

#define N_TOK 32768
#define LC 32
#define NCHUNK (N_TOK / LC)   // 1024

typedef short short8 __attribute__((ext_vector_type(8)));   // 8 bf16 (4 VGPRs)
typedef float f32x4 __attribute__((ext_vector_type(4)));

__device__ __forceinline__ float siluf_(float v){ return v / (1.f + __expf(-v)); }
__device__ __forceinline__ float softplusf_(float v){ return v > 20.f ? v : log1pf(__expf(v)); }

__device__ __forceinline__ unsigned f2bfu(float f){
  __hip_bfloat16 h = __float2bfloat16(f);
  return (unsigned)*(unsigned short*)&h;
}

__device__ __forceinline__ float waveRed64(float v){
  #pragma unroll
  for (int m = 1; m < 64; m <<= 1) v += __shfl_xor(v, m);
  return v;
}

// ---------- all weight converts in one launch ----------
__global__ void k_wcvt_all(const float* __restrict__ ipw, const float* __restrict__ opw,
                           const float* __restrict__ w1, const float* __restrict__ w2,
                           const float* __restrict__ xpw,
                           __hip_bfloat16* __restrict__ ipwt, __hip_bfloat16* __restrict__ opwt,
                           __hip_bfloat16* __restrict__ w1t, __hip_bfloat16* __restrict__ w2t,
                           __hip_bfloat16* __restrict__ xpwt){
  int e = blockIdx.x*256 + threadIdx.x;
  if (e < 65536){ int n=e>>7, k=e&127; ipwt[e]=__float2bfloat16(ipw[k*512+n]); }
  else if (e < 98304){ int f=e-65536; int n=f>>8, k=f&255; opwt[f]=__float2bfloat16(opw[k*128+n]); }
  else if (e < 131072){ int f=e-98304; int n=f>>8, k=f&255; w1t[f]=__float2bfloat16(w1[k*128+n]); }
  else if (e < 147456){ int f=e-131072; int n=f>>7, k=f&127; w2t[f]=__float2bfloat16(w2[k*128+n]); }
  else if (e < 159744){ int f=e-147456; int n=f>>8, k=f&255;
                        xpwt[f]=(n<40)?__float2bfloat16(xpw[k*40+n]):__float2bfloat16(0.f); }
}

// ---------- K1: fused rmsnorm(feat)->a0 AND gather+LN->cat[:,128:256] ----------
__global__ void k_gat_rms(const float* __restrict__ feat, const int* __restrict__ ridx,
                          const float* __restrict__ gd, const float* __restrict__ g,
                          const float* __restrict__ b, const float* __restrict__ rmsw,
                          unsigned* __restrict__ catu, unsigned* __restrict__ a0u){
  int row = blockIdx.x*4 + (threadIdx.x>>6);
  int lane = threadIdx.x & 63;
  float2 f2 = ((const float2*)feat)[row*64 + lane];
  float ss = waveRed64(f2.x*f2.x + f2.y*f2.y);
  float is0 = rsqrtf(ss * (1.f/128.f) + 1e-5f);
  float2 w = ((const float2*)rmsw)[lane];
  a0u[row*64 + lane] = f2bfu(f2.x*is0*w.x) | (f2bfu(f2.y*is0*w.y) << 16);
  float ax=0.f, ay=0.f;
  #pragma unroll 4
  for (int k=0;k<16;k++){
    int idx = ridx[row*16+k];
    float ww = gd[row*16+k];
    float2 f = ((const float2*)feat)[idx*64 + lane];
    ax += ww*f.x; ay += ww*f.y;
  }
  float m = waveRed64(ax+ay) * (1.f/128.f);
  float dx = ax-m, dy = ay-m;
  float var = waveRed64(dx*dx+dy*dy) * (1.f/128.f);
  float is = rsqrtf(var + 1e-5f);
  float2 gg = ((const float2*)g)[lane];
  float2 bb = ((const float2*)b)[lane];
  float ox = dx*is*gg.x + bb.x, oy = dy*is*gg.y + bb.y;
  catu[row*128 + 64 + lane] = f2bfu(ox) | (f2bfu(oy) << 16);
}

// ---------- MFMA GEMM: out[M,N] = A[M,K](bf16) @ Wt[N,K](bf16)^T ----------
// MODE 0: + bias? + resid? -> out0 (f32)
// MODE 1: n<256 -> out0 (x, f32); n>=256 -> silu -> out1 (z, bf16)
template<int WM16, int WN16, int MODE>
__global__ __launch_bounds__(256) void k_mfma(const __hip_bfloat16* __restrict__ A,
      const __hip_bfloat16* __restrict__ Wt, int K,
      const float* __restrict__ bias, const float* __restrict__ resid,
      float* __restrict__ out0, __hip_bfloat16* __restrict__ out1, int ldout){
  int tid = threadIdx.x;
  int wave = tid>>6, lane = tid&63;
  int wm = wave>>1, wn = wave&1;
  int lane16 = lane&15, quad = lane>>4;
  int m_w = blockIdx.x*(2*WM16*16) + wm*(WM16*16);
  int n_w = blockIdx.y*(2*WN16*16) + wn*(WN16*16);
  f32x4 acc[WM16][WN16];
  #pragma unroll
  for (int i=0;i<WM16;i++)
    #pragma unroll
    for (int j=0;j<WN16;j++) acc[i][j] = (f32x4){0.f,0.f,0.f,0.f};
  const __hip_bfloat16* Ab = A  + (size_t)(m_w + lane16)*K + quad*8;
  const __hip_bfloat16* Bb = Wt + (size_t)(n_w + lane16)*K + quad*8;
  #pragma unroll 4
  for (int kk=0; kk<K; kk+=32){
    short8 a[WM16], b[WN16];
    #pragma unroll
    for (int i=0;i<WM16;i++) a[i] = *(const short8*)(Ab + (size_t)i*16*K + kk);
    #pragma unroll
    for (int j=0;j<WN16;j++) b[j] = *(const short8*)(Bb + (size_t)j*16*K + kk);
    #pragma unroll
    for (int i=0;i<WM16;i++)
      #pragma unroll
      for (int j=0;j<WN16;j++)
        acc[i][j] = __builtin_amdgcn_mfma_f32_16x16x32_bf16(a[i], b[j], acc[i][j], 0, 0, 0);
  }
  #pragma unroll
  for (int i=0;i<WM16;i++){
    #pragma unroll
    for (int j=0;j<WN16;j++){
      int n = n_w + j*16 + lane16;
      float bv = 0.f;
      if (MODE==0 && bias) bv = bias[n];
      #pragma unroll
      for (int r=0;r<4;r++){
        int m = m_w + i*16 + quad*4 + r;
        float v = acc[i][j][r] + bv;
        if (MODE==0){
          if (resid) v += resid[(size_t)m*ldout + n];
          out0[(size_t)m*ldout + n] = v;
        } else {
          if (n < 256) out0[(size_t)m*256 + n] = v;
          else         out1[(size_t)m*256 + (n-256)] = __float2bfloat16(siluf_(v));
        }
      }
    }
  }
}

// ---------- xproj MFMA: dbc[M,48] = bxsb[M,256] @ xpwt[48,256]^T, split-store ----------
__global__ __launch_bounds__(256) void k_xproj_mfma(const __hip_bfloat16* __restrict__ A,
      const __hip_bfloat16* __restrict__ Wt,
      float* __restrict__ dt8, float* __restrict__ Bm, float* __restrict__ Cm){
  int tid = threadIdx.x;
  int wave = tid>>6, lane = tid&63;
  int lane16 = lane&15, quad = lane>>4;
  int m_w = blockIdx.x*64 + wave*16;
  f32x4 acc[3];
  #pragma unroll
  for (int j=0;j<3;j++) acc[j] = (f32x4){0.f,0.f,0.f,0.f};
  const __hip_bfloat16* Ab = A  + (size_t)(m_w + lane16)*256 + quad*8;
  const __hip_bfloat16* Bb = Wt + (size_t)lane16*256 + quad*8;
  #pragma unroll
  for (int kk=0; kk<256; kk+=32){
    short8 a = *(const short8*)(Ab + kk);
    short8 b0 = *(const short8*)(Bb + kk);
    short8 b1 = *(const short8*)(Bb + 16*256 + kk);
    short8 b2 = *(const short8*)(Bb + 32*256 + kk);
    acc[0] = __builtin_amdgcn_mfma_f32_16x16x32_bf16(a, b0, acc[0], 0, 0, 0);
    acc[1] = __builtin_amdgcn_mfma_f32_16x16x32_bf16(a, b1, acc[1], 0, 0, 0);
    acc[2] = __builtin_amdgcn_mfma_f32_16x16x32_bf16(a, b2, acc[2], 0, 0, 0);
  }
  #pragma unroll
  for (int j=0;j<3;j++){
    int n = j*16 + lane16;
    #pragma unroll
    for (int r=0;r<4;r++){
      int m = m_w + quad*4 + r;
      float v = acc[j][r];
      if (n < 8)       dt8[(size_t)m*8 + n] = v;
      else if (n < 24) Bm[(size_t)m*16 + (n-8)] = v;
      else if (n < 40) Cm[(size_t)m*16 + (n-24)] = v;
    }
  }
}

// ---------- K3: causal depthwise conv + silu, no LDS, 32-t blocks ----------
__global__ void __launch_bounds__(256) k_conv(const float* __restrict__ bx,
      const float* __restrict__ cw, const float* __restrict__ cb,
      float* __restrict__ bxs, __hip_bfloat16* __restrict__ bxsb){
  int r0 = blockIdx.x*32;
  int d = threadIdx.x;
  float w0=cw[d*4], w1=cw[d*4+1], w2=cw[d*4+2], w3=cw[d*4+3], bb=cb[d];
  float a0 = (r0 >= 3) ? bx[(size_t)(r0-3)*256 + d] : 0.f;
  float a1 = (r0 >= 2) ? bx[(size_t)(r0-2)*256 + d] : 0.f;
  float a2 = (r0 >= 1) ? bx[(size_t)(r0-1)*256 + d] : 0.f;
  #pragma unroll 4
  for (int t=0;t<32;t++){
    float a3 = bx[(size_t)(r0+t)*256 + d];
    float xc = bb + w0*a0 + w1*a1 + w2*a2 + w3*a3;
    float sv = siluf_(xc);
    bxs[(size_t)(r0+t)*256 + d] = sv;
    bxsb[(size_t)(r0+t)*256 + d] = __float2bfloat16(sv);
    a0=a1; a1=a2; a2=a3;
  }
}

// ---------- K4b: delta = softplus(dt8 @ dt_proj_w + dt_proj_b) ----------
__global__ void __launch_bounds__(256) k_delta(const float* __restrict__ dt8,
      const float* __restrict__ dtw, const float* __restrict__ dtb, float* __restrict__ delta){
  __shared__ float T8[64][8];
  __shared__ float Wd[8][256];
  int r0 = blockIdx.x*64;
  int tid = threadIdx.x;
  for (int e=tid; e<512; e+=256){ int r=e>>3, c=e&7; T8[r][c] = dt8[(r0+r)*8 + c]; }
  for (int e=tid; e<2048; e+=256){ int j=e>>8, d=e&255; Wd[j][d] = dtw[j*256 + d]; }
  __syncthreads();
  int d = tid;
  float bb = dtb[d];
  for (int r=0;r<64;r++){
    float acc = bb;
    #pragma unroll
    for (int j=0;j<8;j++) acc += T8[r][j]*Wd[j][d];
    delta[(r0+r)*256 + d] = softplusf_(acc);
  }
}

// ---------- K5: scan pass 1 — one wave per (chunk, 64-channel group), 16 states/lane ----------
__global__ __launch_bounds__(64) void k_scan1(const float* __restrict__ delta,
      const float* __restrict__ bxs, const float* __restrict__ Bm,
      const float* __restrict__ A_log, float* __restrict__ Pc, float* __restrict__ Hc){
  int g = blockIdx.x;
  int d = blockIdx.y*64 + threadIdx.x;
  int t0 = g*LC;
  float aS[16];
  #pragma unroll
  for (int s=0;s<16;s++) aS[s] = -__expf(A_log[d*16+s]);
  float h[16] = {};
  float dsum = 0.f;
  #pragma unroll 4
  for (int t=0;t<LC;t++){
    float dv = delta[(size_t)(t0+t)*256 + d];
    float xv = bxs[(size_t)(t0+t)*256 + d];
    const float4* Bp = (const float4*)(Bm + (size_t)(t0+t)*16);
    float4 b0=Bp[0], b1=Bp[1], b2=Bp[2], b3=Bp[3];
    float bl[16] = {b0.x,b0.y,b0.z,b0.w, b1.x,b1.y,b1.z,b1.w,
                    b2.x,b2.y,b2.z,b2.w, b3.x,b3.y,b3.z,b3.w};
    dsum += dv;
    float dx_ = dv*xv;
    #pragma unroll
    for (int s=0;s<16;s++) h[s] = __expf(dv*aS[s])*h[s] + dx_*bl[s];
  }
  size_t base = (size_t)g*4096 + (size_t)d*16;
  float4* Pd = (float4*)(Pc + base);
  float4* Hd = (float4*)(Hc + base);
  #pragma unroll
  for (int q=0;q<4;q++){
    Pd[q] = make_float4(__expf(dsum*aS[q*4]), __expf(dsum*aS[q*4+1]),
                        __expf(dsum*aS[q*4+2]), __expf(dsum*aS[q*4+3]));
    Hd[q] = make_float4(h[q*4], h[q*4+1], h[q*4+2], h[q*4+3]);
  }
}

// ---------- K6: carry scan across chunks (in place: HC holds H on entry, Cr on exit) ----------
__global__ __launch_bounds__(64) void k_carry(const float* __restrict__ Pc, float* HC){
  int ch = blockIdx.x*64 + threadIdx.x;
  float c = 0.f;
  #pragma unroll 8
  for (int g=0; g<NCHUNK; g++){
    size_t a = (size_t)g*4096 + ch;
    float p  = Pc[a];
    float hh = HC[a];
    HC[a] = c;
    c = p*c + hh;
  }
}

// ---------- K7: scan pass 2 — seeded local scan, final gated y (bf16), 16 states/lane ----------
__global__ __launch_bounds__(64) void k_scan2(const float* __restrict__ delta,
      const float* __restrict__ bxs, const float* __restrict__ Bm, const float* __restrict__ Cm,
      const __hip_bfloat16* __restrict__ zb, const float* __restrict__ A_log,
      const float* __restrict__ Dp, const float* __restrict__ Cr,
      __hip_bfloat16* __restrict__ yb){
  int g = blockIdx.x;
  int d = blockIdx.y*64 + threadIdx.x;
  int t0 = g*LC;
  float aS[16];
  #pragma unroll
  for (int s=0;s<16;s++) aS[s] = -__expf(A_log[d*16+s]);
  float h[16];
  {
    const float4* hc = (const float4*)(Cr + (size_t)g*4096 + (size_t)d*16);
    #pragma unroll
    for (int q=0;q<4;q++){
      float4 v = hc[q];
      h[q*4]=v.x; h[q*4+1]=v.y; h[q*4+2]=v.z; h[q*4+3]=v.w;
    }
  }
  float dpar = Dp[d];
  #pragma unroll 4
  for (int t=0;t<LC;t++){
    float dv = delta[(size_t)(t0+t)*256 + d];
    float xv = bxs[(size_t)(t0+t)*256 + d];
    float zv = __bfloat162float(zb[(size_t)(t0+t)*256 + d]);
    const float4* Bp = (const float4*)(Bm + (size_t)(t0+t)*16);
    const float4* Cp = (const float4*)(Cm + (size_t)(t0+t)*16);
    float4 b0=Bp[0], b1=Bp[1], b2=Bp[2], b3=Bp[3];
    float4 c0=Cp[0], c1=Cp[1], c2=Cp[2], c3=Cp[3];
    float bl[16] = {b0.x,b0.y,b0.z,b0.w, b1.x,b1.y,b1.z,b1.w,
                    b2.x,b2.y,b2.z,b2.w, b3.x,b3.y,b3.z,b3.w};
    float cl[16] = {c0.x,c0.y,c0.z,c0.w, c1.x,c1.y,c1.z,c1.w,
                    c2.x,c2.y,c2.z,c2.w, c3.x,c3.y,c3.z,c3.w};
    float dx_ = dv*xv;
    float yv = 0.f;
    #pragma unroll
    for (int s=0;s<16;s++){
      h[s] = __expf(dv*aS[s])*h[s] + dx_*bl[s];
      yv += h[s]*cl[s];
    }
    yb[(size_t)(t0+t)*256 + d] = __float2bfloat16((yv + dpar*xv)*zv);
  }
}

// ---------- LayerNorm (fp32 in) -> bf16 out, optional relu ----------
__global__ void k_ln_bf16(const float* __restrict__ in, const float* __restrict__ g,
                          const float* __restrict__ b, unsigned* __restrict__ outu,
                          int ldh_u, int dorelu){
  int row = blockIdx.x*4 + (threadIdx.x>>6);
  int lane = threadIdx.x & 63;
  float2 v = ((const float2*)in)[row*64 + lane];
  float m = waveRed64(v.x+v.y) * (1.f/128.f);
  float dx = v.x - m, dy = v.y - m;
  float var = waveRed64(dx*dx + dy*dy) * (1.f/128.f);
  float is = rsqrtf(var + 1e-5f);
  float2 gg = ((const float2*)g)[lane];
  float2 bb = ((const float2*)b)[lane];
  float ox = dx*is*gg.x + bb.x;
  float oy = dy*is*gg.y + bb.y;
  if (dorelu){ ox = fmaxf(ox, 0.f); oy = fmaxf(oy, 0.f); }
  outu[row*ldh_u + lane] = f2bfu(ox) | (f2bfu(oy) << 16);
}

extern "C" void kernel_launch(void* const* d_in, const int* in_sizes, int n_in,
                              void* d_out, int out_size, void* d_ws, size_t ws_size,
                              hipStream_t stream){
  const float* feat = (const float*)d_in[0];
  const int*   ridx = (const int*)d_in[2];
  const float* gd   = (const float*)d_in[3];
  const float* ipw  = (const float*)d_in[5];
  const float* cw   = (const float*)d_in[6];
  const float* cb   = (const float*)d_in[7];
  const float* xpw  = (const float*)d_in[8];
  const float* dtw  = (const float*)d_in[9];
  const float* dtb  = (const float*)d_in[10];
  const float* alog = (const float*)d_in[11];
  const float* dpar = (const float*)d_in[12];
  const float* opw  = (const float*)d_in[13];
  const float* rmsw = (const float*)d_in[14];
  const float* lng  = (const float*)d_in[15];
  const float* lnb  = (const float*)d_in[16];
  const float* w1   = (const float*)d_in[17];
  const float* b1   = (const float*)d_in[18];
  const float* lag  = (const float*)d_in[19];
  const float* lab  = (const float*)d_in[20];
  const float* w2   = (const float*)d_in[21];
  const float* b2   = (const float*)d_in[22];
  float* out = (float*)d_out;

  float* ws    = (float*)d_ws;
  float* bx    = ws;                        // N*256 f32 (32MB): pre-conv x; then Pc|HcCr
  float* zreg  = bx   + (size_t)N_TOK*256;  // 32MB region: zb (bf16, 16MB) now; h1 (bf16) later
  float* bxs   = zreg + (size_t)N_TOK*256;  // N*256 f32 silu(conv(x)); a0 (bf16) pre-conv
  float* delta = bxs  + (size_t)N_TOK*256;  // N*256 f32; later t1 (f32 N*128)
  float* dt8   = delta + (size_t)N_TOK*256; // N*8
  float* Bm    = dt8  + (size_t)N_TOK*8;    // N*16
  float* Cm    = Bm   + (size_t)N_TOK*16;   // N*16
  __hip_bfloat16* cat  = (__hip_bfloat16*)(Cm + (size_t)N_TOK*16);  // N*256 bf16
  __hip_bfloat16* bxsb = cat  + (size_t)N_TOK*256;                  // N*256 bf16; yb later
  __hip_bfloat16* ipwt = bxsb + (size_t)N_TOK*256;                  // 512*128
  __hip_bfloat16* opwt = ipwt + 512*128;
  __hip_bfloat16* w1t  = opwt + 128*256;
  __hip_bfloat16* w2t  = w1t  + 128*256;
  __hip_bfloat16* xpwt = w2t  + 128*128;                            // 48*256
  // aliases:
  float* Pc   = bx;                                     // NCHUNK*4096 f32 = 16MB
  float* HcCr = bx + (size_t)NCHUNK*4096;               // 16MB (H, then Cr in place)
  __hip_bfloat16* zb = (__hip_bfloat16*)zreg;           // N*256 bf16 silu(z)
  __hip_bfloat16* a0 = (__hip_bfloat16*)bxs;            // N*128 bf16 (dead once conv writes bxs)
  __hip_bfloat16* yb = bxsb;                            // N*256 bf16 (bxsb dead after xproj)
  float*          t1 = delta;                           // N*128 f32 (delta dead after scan2)
  __hip_bfloat16* h1 = (__hip_bfloat16*)zreg;           // N*128 bf16 (zb dead after scan2)

  hipLaunchKernelGGL(k_wcvt_all, dim3(624), dim3(256), 0, stream,
                     ipw, opw, w1, w2, xpw, ipwt, opwt, w1t, w2t, xpwt);
  hipLaunchKernelGGL(k_gat_rms,  dim3(N_TOK/4), dim3(256), 0, stream,
                     feat, ridx, gd, lng, lnb, rmsw, (unsigned*)cat, (unsigned*)a0);
  hipLaunchKernelGGL((k_mfma<4,4,1>), dim3(N_TOK/128, 4), dim3(256), 0, stream,
                     a0, ipwt, 128, (const float*)nullptr, (const float*)nullptr, bx, zb, 256);
  hipLaunchKernelGGL(k_conv,  dim3(N_TOK/32), dim3(256), 0, stream, bx, cw, cb, bxs, bxsb);
  hipLaunchKernelGGL(k_xproj_mfma, dim3(N_TOK/64), dim3(256), 0, stream, bxsb, xpwt, dt8, Bm, Cm);
  hipLaunchKernelGGL(k_delta, dim3(N_TOK/64), dim3(256), 0, stream, dt8, dtw, dtb, delta);
  hipLaunchKernelGGL(k_scan1, dim3(NCHUNK, 4), dim3(64), 0, stream, delta, bxs, Bm, alog, Pc, HcCr);
  hipLaunchKernelGGL(k_carry, dim3(64), dim3(64), 0, stream, Pc, HcCr);
  hipLaunchKernelGGL(k_scan2, dim3(NCHUNK, 4), dim3(64), 0, stream, delta, bxs, Bm, Cm, zb, alog, dpar, HcCr, yb);
  hipLaunchKernelGGL((k_mfma<2,4,0>), dim3(N_TOK/64, 1), dim3(256), 0, stream,
                     yb, opwt, 256, (const float*)nullptr, feat, t1, (__hip_bfloat16*)nullptr, 128);
  hipLaunchKernelGGL(k_ln_bf16, dim3(N_TOK/4), dim3(256), 0, stream, t1, lng, lnb, (unsigned*)cat, 128, 0);
  hipLaunchKernelGGL((k_mfma<2,4,0>), dim3(N_TOK/64, 1), dim3(256), 0, stream,
                     cat, w1t, 256, b1, (const float*)nullptr, t1, (__hip_bfloat16*)nullptr, 128);
  hipLaunchKernelGGL(k_ln_bf16, dim3(N_TOK/4), dim3(256), 0, stream, t1, lag, lab, (unsigned*)h1, 64, 1);
  hipLaunchKernelGGL((k_mfma<2,4,0>), dim3(N_TOK/64, 1), dim3(256), 0, stream,
                     h1, w2t, 128, b2, (const float*)nullptr, out, (__hip_bfloat16*)nullptr, 128);
}

// Round 7
// 395.476 us; speedup vs baseline: 1.1050x; 1.1050x over previous
//
#include <hip/hip_runtime.h>
#include <hip/hip_bf16.h>
#include <math.h>

#define N_TOK 32768
#define LC 32
#define NCHUNK (N_TOK / LC)   // 1024
#define NSEG 32
#define SEGLEN (NCHUNK / NSEG) // 32

typedef short short8 __attribute__((ext_vector_type(8)));   // 8 bf16 (4 VGPRs)
typedef float f32x4 __attribute__((ext_vector_type(4)));

__device__ __forceinline__ float siluf_(float v){ return v / (1.f + __expf(-v)); }
__device__ __forceinline__ float softplusf_(float v){ return v > 20.f ? v : log1pf(__expf(v)); }

__device__ __forceinline__ unsigned f2bfu(float f){
  __hip_bfloat16 h = __float2bfloat16(f);
  return (unsigned)*(unsigned short*)&h;
}

__device__ __forceinline__ float waveRed64(float v){
  #pragma unroll
  for (int m = 1; m < 64; m <<= 1) v += __shfl_xor(v, m);
  return v;
}

// ---------- all weight converts in one launch ----------
__global__ void k_wcvt_all(const float* __restrict__ ipw, const float* __restrict__ opw,
                           const float* __restrict__ w1, const float* __restrict__ w2,
                           const float* __restrict__ xpw,
                           __hip_bfloat16* __restrict__ ipwt, __hip_bfloat16* __restrict__ opwt,
                           __hip_bfloat16* __restrict__ w1t, __hip_bfloat16* __restrict__ w2t,
                           __hip_bfloat16* __restrict__ xpwt){
  int e = blockIdx.x*256 + threadIdx.x;
  if (e < 65536){ int n=e>>7, k=e&127; ipwt[e]=__float2bfloat16(ipw[k*512+n]); }
  else if (e < 98304){ int f=e-65536; int n=f>>8, k=f&255; opwt[f]=__float2bfloat16(opw[k*128+n]); }
  else if (e < 131072){ int f=e-98304; int n=f>>8, k=f&255; w1t[f]=__float2bfloat16(w1[k*128+n]); }
  else if (e < 147456){ int f=e-131072; int n=f>>7, k=f&127; w2t[f]=__float2bfloat16(w2[k*128+n]); }
  else if (e < 159744){ int f=e-147456; int n=f>>8, k=f&255;
                        xpwt[f]=(n<40)?__float2bfloat16(xpw[k*40+n]):__float2bfloat16(0.f); }
}

// ---------- K1: fused rmsnorm(feat)->a0 AND gather+LN->cat[:,128:256] ----------
__global__ void k_gat_rms(const float* __restrict__ feat, const int* __restrict__ ridx,
                          const float* __restrict__ gd, const float* __restrict__ g,
                          const float* __restrict__ b, const float* __restrict__ rmsw,
                          unsigned* __restrict__ catu, unsigned* __restrict__ a0u){
  int row = blockIdx.x*4 + (threadIdx.x>>6);
  int lane = threadIdx.x & 63;
  float2 f2 = ((const float2*)feat)[row*64 + lane];
  float ss = waveRed64(f2.x*f2.x + f2.y*f2.y);
  float is0 = rsqrtf(ss * (1.f/128.f) + 1e-5f);
  float2 w = ((const float2*)rmsw)[lane];
  a0u[row*64 + lane] = f2bfu(f2.x*is0*w.x) | (f2bfu(f2.y*is0*w.y) << 16);
  float ax=0.f, ay=0.f;
  #pragma unroll 4
  for (int k=0;k<16;k++){
    int idx = ridx[row*16+k];
    float ww = gd[row*16+k];
    float2 f = ((const float2*)feat)[idx*64 + lane];
    ax += ww*f.x; ay += ww*f.y;
  }
  float m = waveRed64(ax+ay) * (1.f/128.f);
  float dx = ax-m, dy = ay-m;
  float var = waveRed64(dx*dx+dy*dy) * (1.f/128.f);
  float is = rsqrtf(var + 1e-5f);
  float2 gg = ((const float2*)g)[lane];
  float2 bb = ((const float2*)b)[lane];
  float ox = dx*is*gg.x + bb.x, oy = dy*is*gg.y + bb.y;
  catu[row*128 + 64 + lane] = f2bfu(ox) | (f2bfu(oy) << 16);
}

// ---------- MFMA GEMM: out[M,N] = A[M,K](bf16) @ Wt[N,K](bf16)^T ----------
// MODE 0: + bias? + resid? -> out0 (f32)
// MODE 1: n<256 -> out0 (x, f32); n>=256 -> silu -> out1 (z, bf16)
template<int WM16, int WN16, int MODE>
__global__ __launch_bounds__(256) void k_mfma(const __hip_bfloat16* __restrict__ A,
      const __hip_bfloat16* __restrict__ Wt, int K,
      const float* __restrict__ bias, const float* __restrict__ resid,
      float* __restrict__ out0, __hip_bfloat16* __restrict__ out1, int ldout){
  int tid = threadIdx.x;
  int wave = tid>>6, lane = tid&63;
  int wm = wave>>1, wn = wave&1;
  int lane16 = lane&15, quad = lane>>4;
  int m_w = blockIdx.x*(2*WM16*16) + wm*(WM16*16);
  int n_w = blockIdx.y*(2*WN16*16) + wn*(WN16*16);
  f32x4 acc[WM16][WN16];
  #pragma unroll
  for (int i=0;i<WM16;i++)
    #pragma unroll
    for (int j=0;j<WN16;j++) acc[i][j] = (f32x4){0.f,0.f,0.f,0.f};
  const __hip_bfloat16* Ab = A  + (size_t)(m_w + lane16)*K + quad*8;
  const __hip_bfloat16* Bb = Wt + (size_t)(n_w + lane16)*K + quad*8;
  #pragma unroll 4
  for (int kk=0; kk<K; kk+=32){
    short8 a[WM16], b[WN16];
    #pragma unroll
    for (int i=0;i<WM16;i++) a[i] = *(const short8*)(Ab + (size_t)i*16*K + kk);
    #pragma unroll
    for (int j=0;j<WN16;j++) b[j] = *(const short8*)(Bb + (size_t)j*16*K + kk);
    #pragma unroll
    for (int i=0;i<WM16;i++)
      #pragma unroll
      for (int j=0;j<WN16;j++)
        acc[i][j] = __builtin_amdgcn_mfma_f32_16x16x32_bf16(a[i], b[j], acc[i][j], 0, 0, 0);
  }
  #pragma unroll
  for (int i=0;i<WM16;i++){
    #pragma unroll
    for (int j=0;j<WN16;j++){
      int n = n_w + j*16 + lane16;
      float bv = 0.f;
      if (MODE==0 && bias) bv = bias[n];
      #pragma unroll
      for (int r=0;r<4;r++){
        int m = m_w + i*16 + quad*4 + r;
        float v = acc[i][j][r] + bv;
        if (MODE==0){
          if (resid) v += resid[(size_t)m*ldout + n];
          out0[(size_t)m*ldout + n] = v;
        } else {
          if (n < 256) out0[(size_t)m*256 + n] = v;
          else         out1[(size_t)m*256 + (n-256)] = __float2bfloat16(siluf_(v));
        }
      }
    }
  }
}

// ---------- xproj MFMA: dbc[M,48] = bxsb[M,256] @ xpwt[48,256]^T, split-store ----------
__global__ __launch_bounds__(256) void k_xproj_mfma(const __hip_bfloat16* __restrict__ A,
      const __hip_bfloat16* __restrict__ Wt,
      float* __restrict__ dt8, float* __restrict__ Bm, float* __restrict__ Cm){
  int tid = threadIdx.x;
  int wave = tid>>6, lane = tid&63;
  int lane16 = lane&15, quad = lane>>4;
  int m_w = blockIdx.x*64 + wave*16;
  f32x4 acc[3];
  #pragma unroll
  for (int j=0;j<3;j++) acc[j] = (f32x4){0.f,0.f,0.f,0.f};
  const __hip_bfloat16* Ab = A  + (size_t)(m_w + lane16)*256 + quad*8;
  const __hip_bfloat16* Bb = Wt + (size_t)lane16*256 + quad*8;
  #pragma unroll
  for (int kk=0; kk<256; kk+=32){
    short8 a = *(const short8*)(Ab + kk);
    short8 b0 = *(const short8*)(Bb + kk);
    short8 b1 = *(const short8*)(Bb + 16*256 + kk);
    short8 b2 = *(const short8*)(Bb + 32*256 + kk);
    acc[0] = __builtin_amdgcn_mfma_f32_16x16x32_bf16(a, b0, acc[0], 0, 0, 0);
    acc[1] = __builtin_amdgcn_mfma_f32_16x16x32_bf16(a, b1, acc[1], 0, 0, 0);
    acc[2] = __builtin_amdgcn_mfma_f32_16x16x32_bf16(a, b2, acc[2], 0, 0, 0);
  }
  #pragma unroll
  for (int j=0;j<3;j++){
    int n = j*16 + lane16;
    #pragma unroll
    for (int r=0;r<4;r++){
      int m = m_w + quad*4 + r;
      float v = acc[j][r];
      if (n < 8)       dt8[(size_t)m*8 + n] = v;
      else if (n < 24) Bm[(size_t)m*16 + (n-8)] = v;
      else if (n < 40) Cm[(size_t)m*16 + (n-24)] = v;
    }
  }
}

// ---------- K3: causal depthwise conv + silu, no LDS, 32-t blocks ----------
__global__ void __launch_bounds__(256) k_conv(const float* __restrict__ bx,
      const float* __restrict__ cw, const float* __restrict__ cb,
      float* __restrict__ bxs, __hip_bfloat16* __restrict__ bxsb){
  int r0 = blockIdx.x*32;
  int d = threadIdx.x;
  float w0=cw[d*4], w1=cw[d*4+1], w2=cw[d*4+2], w3=cw[d*4+3], bb=cb[d];
  float a0 = (r0 >= 3) ? bx[(size_t)(r0-3)*256 + d] : 0.f;
  float a1 = (r0 >= 2) ? bx[(size_t)(r0-2)*256 + d] : 0.f;
  float a2 = (r0 >= 1) ? bx[(size_t)(r0-1)*256 + d] : 0.f;
  #pragma unroll 4
  for (int t=0;t<32;t++){
    float a3 = bx[(size_t)(r0+t)*256 + d];
    float xc = bb + w0*a0 + w1*a1 + w2*a2 + w3*a3;
    float sv = siluf_(xc);
    bxs[(size_t)(r0+t)*256 + d] = sv;
    bxsb[(size_t)(r0+t)*256 + d] = __float2bfloat16(sv);
    a0=a1; a1=a2; a2=a3;
  }
}

// ---------- K4b: delta = softplus(dt8 @ dt_proj_w + dt_proj_b) ----------
__global__ void __launch_bounds__(256) k_delta(const float* __restrict__ dt8,
      const float* __restrict__ dtw, const float* __restrict__ dtb, float* __restrict__ delta){
  __shared__ float T8[64][8];
  __shared__ float Wd[8][256];
  int r0 = blockIdx.x*64;
  int tid = threadIdx.x;
  for (int e=tid; e<512; e+=256){ int r=e>>3, c=e&7; T8[r][c] = dt8[(r0+r)*8 + c]; }
  for (int e=tid; e<2048; e+=256){ int j=e>>8, d=e&255; Wd[j][d] = dtw[j*256 + d]; }
  __syncthreads();
  int d = tid;
  float bb = dtb[d];
  for (int r=0;r<64;r++){
    float acc = bb;
    #pragma unroll
    for (int j=0;j<8;j++) acc += T8[r][j]*Wd[j][d];
    delta[(r0+r)*256 + d] = softplusf_(acc);
  }
}

// ---------- K5: scan pass 1 — one wave per (chunk, 64-channel group), 16 states/lane ----------
__global__ __launch_bounds__(64) void k_scan1(const float* __restrict__ delta,
      const float* __restrict__ bxs, const float* __restrict__ Bm,
      const float* __restrict__ A_log, float* __restrict__ Pc, float* __restrict__ Hc){
  int g = blockIdx.x;
  int d = blockIdx.y*64 + threadIdx.x;
  int t0 = g*LC;
  float aS[16];
  #pragma unroll
  for (int s=0;s<16;s++) aS[s] = -__expf(A_log[d*16+s]);
  float h[16] = {};
  float dsum = 0.f;
  #pragma unroll 4
  for (int t=0;t<LC;t++){
    float dv = delta[(size_t)(t0+t)*256 + d];
    float xv = bxs[(size_t)(t0+t)*256 + d];
    const float4* Bp = (const float4*)(Bm + (size_t)(t0+t)*16);
    float4 b0=Bp[0], b1=Bp[1], b2=Bp[2], b3=Bp[3];
    float bl[16] = {b0.x,b0.y,b0.z,b0.w, b1.x,b1.y,b1.z,b1.w,
                    b2.x,b2.y,b2.z,b2.w, b3.x,b3.y,b3.z,b3.w};
    dsum += dv;
    float dx_ = dv*xv;
    #pragma unroll
    for (int s=0;s<16;s++) h[s] = __expf(dv*aS[s])*h[s] + dx_*bl[s];
  }
  size_t base = (size_t)g*4096 + (size_t)d*16;
  float4* Pd = (float4*)(Pc + base);
  float4* Hd = (float4*)(Hc + base);
  #pragma unroll
  for (int q=0;q<4;q++){
    Pd[q] = make_float4(__expf(dsum*aS[q*4]), __expf(dsum*aS[q*4+1]),
                        __expf(dsum*aS[q*4+2]), __expf(dsum*aS[q*4+3]));
    Hd[q] = make_float4(h[q*4], h[q*4+1], h[q*4+2], h[q*4+3]);
  }
}

// ---------- K6a: within-segment prefix transform (in place) + segment aggregates ----------
// On entry: Pc[g], Hc[g] are per-chunk (decay, state). On exit: Pc[g] = product of
// decays over chunks [seg_start, g), Hc[g] = carry within segment before g.
__global__ __launch_bounds__(256) void k_carry_a(float* __restrict__ Pc, float* __restrict__ Hc,
      float* __restrict__ Pagg, float* __restrict__ Hagg){
  int seg = blockIdx.x;
  int ch  = blockIdx.y*256 + threadIdx.x;
  float pp = 1.f, c = 0.f;
  int g0 = seg*SEGLEN;
  #pragma unroll 4
  for (int i=0;i<SEGLEN;i++){
    size_t a = (size_t)(g0+i)*4096 + ch;
    float p  = Pc[a];
    float hh = Hc[a];
    Pc[a] = pp;
    Hc[a] = c;
    pp *= p;
    c = p*c + hh;
  }
  size_t sa = (size_t)seg*4096 + ch;
  Pagg[sa] = pp;
  Hagg[sa] = c;
}

// ---------- K6b: scan over segment aggregates -> Cseg (carry before each segment) ----------
__global__ __launch_bounds__(256) void k_carry_b(const float* __restrict__ Pagg,
      const float* __restrict__ Hagg, float* __restrict__ Cseg){
  int ch = blockIdx.x*256 + threadIdx.x;
  float c = 0.f;
  #pragma unroll
  for (int s=0;s<NSEG;s++){
    size_t a = (size_t)s*4096 + ch;
    Cseg[a] = c;
    c = Pagg[a]*c + Hagg[a];
  }
}

// ---------- K7: scan pass 2 — seed = Pprefix*Cseg + Hprefix, final gated y (bf16) ----------
__global__ __launch_bounds__(64) void k_scan2(const float* __restrict__ delta,
      const float* __restrict__ bxs, const float* __restrict__ Bm, const float* __restrict__ Cm,
      const __hip_bfloat16* __restrict__ zb, const float* __restrict__ A_log,
      const float* __restrict__ Dp, const float* __restrict__ Pc, const float* __restrict__ Hc,
      const float* __restrict__ Cseg, __hip_bfloat16* __restrict__ yb){
  int g = blockIdx.x;
  int d = blockIdx.y*64 + threadIdx.x;
  int t0 = g*LC;
  int seg = g / SEGLEN;
  float aS[16];
  #pragma unroll
  for (int s=0;s<16;s++) aS[s] = -__expf(A_log[d*16+s]);
  float h[16];
  {
    const float4* pp = (const float4*)(Pc + (size_t)g*4096 + (size_t)d*16);
    const float4* hp = (const float4*)(Hc + (size_t)g*4096 + (size_t)d*16);
    const float4* cs = (const float4*)(Cseg + (size_t)seg*4096 + (size_t)d*16);
    #pragma unroll
    for (int q=0;q<4;q++){
      float4 P = pp[q], H = hp[q], C = cs[q];
      h[q*4+0] = P.x*C.x + H.x;
      h[q*4+1] = P.y*C.y + H.y;
      h[q*4+2] = P.z*C.z + H.z;
      h[q*4+3] = P.w*C.w + H.w;
    }
  }
  float dpar = Dp[d];
  #pragma unroll 4
  for (int t=0;t<LC;t++){
    float dv = delta[(size_t)(t0+t)*256 + d];
    float xv = bxs[(size_t)(t0+t)*256 + d];
    float zv = __bfloat162float(zb[(size_t)(t0+t)*256 + d]);
    const float4* Bp = (const float4*)(Bm + (size_t)(t0+t)*16);
    const float4* Cp = (const float4*)(Cm + (size_t)(t0+t)*16);
    float4 b0=Bp[0], b1=Bp[1], b2=Bp[2], b3=Bp[3];
    float4 c0=Cp[0], c1=Cp[1], c2=Cp[2], c3=Cp[3];
    float bl[16] = {b0.x,b0.y,b0.z,b0.w, b1.x,b1.y,b1.z,b1.w,
                    b2.x,b2.y,b2.z,b2.w, b3.x,b3.y,b3.z,b3.w};
    float cl[16] = {c0.x,c0.y,c0.z,c0.w, c1.x,c1.y,c1.z,c1.w,
                    c2.x,c2.y,c2.z,c2.w, c3.x,c3.y,c3.z,c3.w};
    float dx_ = dv*xv;
    float yv = 0.f;
    #pragma unroll
    for (int s=0;s<16;s++){
      h[s] = __expf(dv*aS[s])*h[s] + dx_*bl[s];
      yv += h[s]*cl[s];
    }
    yb[(size_t)(t0+t)*256 + d] = __float2bfloat16((yv + dpar*xv)*zv);
  }
}

// ---------- LayerNorm (fp32 in) -> bf16 out, optional relu ----------
__global__ void k_ln_bf16(const float* __restrict__ in, const float* __restrict__ g,
                          const float* __restrict__ b, unsigned* __restrict__ outu,
                          int ldh_u, int dorelu){
  int row = blockIdx.x*4 + (threadIdx.x>>6);
  int lane = threadIdx.x & 63;
  float2 v = ((const float2*)in)[row*64 + lane];
  float m = waveRed64(v.x+v.y) * (1.f/128.f);
  float dx = v.x - m, dy = v.y - m;
  float var = waveRed64(dx*dx + dy*dy) * (1.f/128.f);
  float is = rsqrtf(var + 1e-5f);
  float2 gg = ((const float2*)g)[lane];
  float2 bb = ((const float2*)b)[lane];
  float ox = dx*is*gg.x + bb.x;
  float oy = dy*is*gg.y + bb.y;
  if (dorelu){ ox = fmaxf(ox, 0.f); oy = fmaxf(oy, 0.f); }
  outu[row*ldh_u + lane] = f2bfu(ox) | (f2bfu(oy) << 16);
}

extern "C" void kernel_launch(void* const* d_in, const int* in_sizes, int n_in,
                              void* d_out, int out_size, void* d_ws, size_t ws_size,
                              hipStream_t stream){
  const float* feat = (const float*)d_in[0];
  const int*   ridx = (const int*)d_in[2];
  const float* gd   = (const float*)d_in[3];
  const float* ipw  = (const float*)d_in[5];
  const float* cw   = (const float*)d_in[6];
  const float* cb   = (const float*)d_in[7];
  const float* xpw  = (const float*)d_in[8];
  const float* dtw  = (const float*)d_in[9];
  const float* dtb  = (const float*)d_in[10];
  const float* alog = (const float*)d_in[11];
  const float* dpar = (const float*)d_in[12];
  const float* opw  = (const float*)d_in[13];
  const float* rmsw = (const float*)d_in[14];
  const float* lng  = (const float*)d_in[15];
  const float* lnb  = (const float*)d_in[16];
  const float* w1   = (const float*)d_in[17];
  const float* b1   = (const float*)d_in[18];
  const float* lag  = (const float*)d_in[19];
  const float* lab  = (const float*)d_in[20];
  const float* w2   = (const float*)d_in[21];
  const float* b2   = (const float*)d_in[22];
  float* out = (float*)d_out;

  float* ws    = (float*)d_ws;
  float* bx    = ws;                        // N*256 f32 (32MB): pre-conv x; then Pc|Hc
  float* zreg  = bx   + (size_t)N_TOK*256;  // 32MB region: zb (bf16, 16MB); h1 (bf16) later
  float* bxs   = zreg + (size_t)N_TOK*256;  // N*256 f32 silu(conv(x)); a0 (bf16) pre-conv
  float* delta = bxs  + (size_t)N_TOK*256;  // N*256 f32; later t1 (f32 N*128)
  float* dt8   = delta + (size_t)N_TOK*256; // N*8
  float* Bm    = dt8  + (size_t)N_TOK*8;    // N*16
  float* Cm    = Bm   + (size_t)N_TOK*16;   // N*16
  __hip_bfloat16* cat  = (__hip_bfloat16*)(Cm + (size_t)N_TOK*16);  // N*256 bf16
  __hip_bfloat16* bxsb = cat  + (size_t)N_TOK*256;                  // N*256 bf16; yb later
  __hip_bfloat16* ipwt = bxsb + (size_t)N_TOK*256;                  // 512*128
  __hip_bfloat16* opwt = ipwt + 512*128;
  __hip_bfloat16* w1t  = opwt + 128*256;
  __hip_bfloat16* w2t  = w1t  + 128*256;
  __hip_bfloat16* xpwt = w2t  + 128*128;                            // 48*256
  float* Pagg = (float*)(xpwt + 48*256);    // NSEG*4096 f32 = 512KB
  float* Hagg = Pagg + (size_t)NSEG*4096;   // 512KB
  float* Cseg = Hagg + (size_t)NSEG*4096;   // 512KB
  // aliases:
  float* Pc   = bx;                                     // NCHUNK*4096 f32 = 16MB
  float* Hc   = bx + (size_t)NCHUNK*4096;               // 16MB (per-chunk H -> prefix H)
  __hip_bfloat16* zb = (__hip_bfloat16*)zreg;           // N*256 bf16 silu(z)
  __hip_bfloat16* a0 = (__hip_bfloat16*)bxs;            // N*128 bf16 (dead once conv writes bxs)
  __hip_bfloat16* yb = bxsb;                            // N*256 bf16 (bxsb dead after xproj)
  float*          t1 = delta;                           // N*128 f32 (delta dead after scan2)
  __hip_bfloat16* h1 = (__hip_bfloat16*)zreg;           // N*128 bf16 (zb dead after scan2)

  hipLaunchKernelGGL(k_wcvt_all, dim3(624), dim3(256), 0, stream,
                     ipw, opw, w1, w2, xpw, ipwt, opwt, w1t, w2t, xpwt);
  hipLaunchKernelGGL(k_gat_rms,  dim3(N_TOK/4), dim3(256), 0, stream,
                     feat, ridx, gd, lng, lnb, rmsw, (unsigned*)cat, (unsigned*)a0);
  hipLaunchKernelGGL((k_mfma<4,4,1>), dim3(N_TOK/128, 4), dim3(256), 0, stream,
                     a0, ipwt, 128, (const float*)nullptr, (const float*)nullptr, bx, zb, 256);
  hipLaunchKernelGGL(k_conv,  dim3(N_TOK/32), dim3(256), 0, stream, bx, cw, cb, bxs, bxsb);
  hipLaunchKernelGGL(k_xproj_mfma, dim3(N_TOK/64), dim3(256), 0, stream, bxsb, xpwt, dt8, Bm, Cm);
  hipLaunchKernelGGL(k_delta, dim3(N_TOK/64), dim3(256), 0, stream, dt8, dtw, dtb, delta);
  hipLaunchKernelGGL(k_scan1, dim3(NCHUNK, 4), dim3(64), 0, stream, delta, bxs, Bm, alog, Pc, Hc);
  hipLaunchKernelGGL(k_carry_a, dim3(NSEG, 16), dim3(256), 0, stream, Pc, Hc, Pagg, Hagg);
  hipLaunchKernelGGL(k_carry_b, dim3(16), dim3(256), 0, stream, Pagg, Hagg, Cseg);
  hipLaunchKernelGGL(k_scan2, dim3(NCHUNK, 4), dim3(64), 0, stream,
                     delta, bxs, Bm, Cm, zb, alog, dpar, Pc, Hc, Cseg, yb);
  hipLaunchKernelGGL((k_mfma<2,4,0>), dim3(N_TOK/64, 1), dim3(256), 0, stream,
                     yb, opwt, 256, (const float*)nullptr, feat, t1, (__hip_bfloat16*)nullptr, 128);
  hipLaunchKernelGGL(k_ln_bf16, dim3(N_TOK/4), dim3(256), 0, stream, t1, lng, lnb, (unsigned*)cat, 128, 0);
  hipLaunchKernelGGL((k_mfma<2,4,0>), dim3(N_TOK/64, 1), dim3(256), 0, stream,
                     cat, w1t, 256, b1, (const float*)nullptr, t1, (__hip_bfloat16*)nullptr, 128);
  hipLaunchKernelGGL(k_ln_bf16, dim3(N_TOK/4), dim3(256), 0, stream, t1, lag, lab, (unsigned*)h1, 64, 1);
  hipLaunchKernelGGL((k_mfma<2,4,0>), dim3(N_TOK/64, 1), dim3(256), 0, stream,
                     h1, w2t, 128, b2, (const float*)nullptr, out, (__hip_bfloat16*)nullptr, 128);
}